// Round 13
// baseline (202.688 us; speedup 1.0000x reference)
//
#include <hip/hip_runtime.h>

// Problem constants
#define BB 16
#define CCH 512
#define CQD 32
#define HH 32
#define WW 32
#define NN 1024
#define PH 34   // padded image dim

typedef __attribute__((ext_vector_type(8))) _Float16 half8;
typedef __attribute__((ext_vector_type(4))) _Float16 half4;
typedef __attribute__((ext_vector_type(4))) float f32x4;

// async global->LDS, 16B per lane; lds dest = wave-uniform base + lane*16
static __device__ __forceinline__ void gload_lds16(const void* g, void* l) {
    __builtin_amdgcn_global_load_lds(
        (const __attribute__((address_space(1))) unsigned int*)g,
        (__attribute__((address_space(3))) unsigned int*)l, 16, 0, 0);
}

// ---------------------------------------------------------------------------
// prep_img: img[b][ci][h][w] fp32 -> imgp[b][34][34][ci] fp16, zero halo.
// grid(34 padded rows, 2 which, 16 b), block 256
// ---------------------------------------------------------------------------
__global__ __launch_bounds__(256) void prep_img_kernel(
    const float* __restrict__ x, const float* __restrict__ y,
    _Float16* __restrict__ xp, _Float16* __restrict__ yp)
{
    const int h = blockIdx.x;            // padded row 0..33
    const int which = blockIdx.y, b = blockIdx.z;
    const float* img = which ? y : x;
    _Float16* row = (which ? yp : xp) + (size_t)(b * PH + h) * PH * CCH;
    const int t = threadIdx.x;
    const int gh = h - 1;

    half8 z;
    #pragma unroll
    for (int u = 0; u < 8; ++u) z[u] = (_Float16)0.f;

    if (gh < 0 || gh >= HH) {            // border row: all zeros (34*512 halves)
        for (int idx = t; idx < PH * CCH / 8; idx += 256)
            *(half8*)&row[(size_t)idx * 8] = z;
        return;
    }

    __shared__ float X[64][33];
    for (int ci0 = 0; ci0 < CCH; ci0 += 64) {
        __syncthreads();
        #pragma unroll
        for (int i = 0; i < 8; ++i) {
            int ci = i * 8 + (t >> 5), w = t & 31;
            X[ci][w] = img[((size_t)(b * CCH + ci0 + ci) * HH + gh) * WW + w];
        }
        __syncthreads();
        int w = t >> 3, g = t & 7;
        half8 o;
        #pragma unroll
        for (int u = 0; u < 8; ++u) o[u] = (_Float16)X[g * 8 + u][w];
        *(half8*)&row[(size_t)(w + 1) * CCH + ci0 + g * 8] = o;
        if (t < 16) {                    // zero pad cols 0 and 33 for this chunk
            int col = (t < 8) ? 0 : 33;
            *(half8*)&row[(size_t)col * CCH + ci0 + (t & 7) * 8] = z;
        }
    }
}

// ---------------------------------------------------------------------------
// prep_w_all: wv -> wvh[0..511], wq -> wqkh[0..31], wk -> wqkh[32..63]
// layout [co][tap*512+ci] fp16. grid(576), block 256.
// ---------------------------------------------------------------------------
__global__ __launch_bounds__(256) void prep_w_all_kernel(
    const float* __restrict__ wv, const float* __restrict__ wq,
    const float* __restrict__ wk, _Float16* __restrict__ wvh,
    _Float16* __restrict__ wqkh)
{
    const int bid = blockIdx.x;
    const float* src;
    _Float16* dst;
    int co_src, co_dst;
    if (bid < 512)      { src = wv; co_src = bid;       dst = wvh;  co_dst = bid; }
    else if (bid < 544) { src = wq; co_src = bid - 512; dst = wqkh; co_dst = bid - 512; }
    else                { src = wk; co_src = bid - 544; dst = wqkh; co_dst = 32 + (bid - 544); }
    for (int idx = threadIdx.x; idx < 4608; idx += 256) {
        int tap = idx / 512, ci = idx - tap * 512;
        dst[(size_t)co_dst * 4608 + idx] = (_Float16)src[(size_t)co_src * 4608 + ci * 9 + tap];
    }
}

// ---------------------------------------------------------------------------
// conv_v_mfma (unchanged R11): W and Y staged via global_load_lds width=16.
// grid(4 pxtiles, 8 cotiles, 16 b), block 256.
// ---------------------------------------------------------------------------
__global__ __launch_bounds__(256, 2) void conv_v_mfma_kernel(
    const _Float16* __restrict__ yp,    // [b][34][34][ci] padded
    const _Float16* __restrict__ wvh,   // [co][tap*512+ci]
    const float* __restrict__ bvb,
    _Float16* __restrict__ vout)        // fp16 [b][co][px]
{
    const int pt  = blockIdx.x;
    const int co0 = blockIdx.y * 64;
    const int b   = blockIdx.z;

    __shared__ __align__(16) _Float16 Wl[64 * 296];   // 2368 16B slots
    __shared__ __align__(16) _Float16 Yl[13824];      // 1728 16B slots (1700 used)

    const int t    = threadIdx.x;
    const int lane = t & 63;
    const int wv4  = t >> 6;
    const int l15  = lane & 15;
    const int kg   = lane >> 4;

    f32x4 acc[4][4];
    #pragma unroll
    for (int m = 0; m < 4; ++m)
        #pragma unroll
        for (int n = 0; n < 4; ++n) {
            f32x4 z = {0.f, 0.f, 0.f, 0.f};
            acc[m][n] = z;
        }

    const int r0p = pt * 8;              // padded start row
    int bbase[4];
    #pragma unroll
    for (int n = 0; n < 4; ++n) {
        int pxl = wv4 * 64 + n * 16 + l15;
        int rl = pxl >> 5, cl = pxl & 31;
        bbase[n] = (rl * 34 + cl) * 40 + kg * 8;
    }
    int abase[4];
    #pragma unroll
    for (int m = 0; m < 4; ++m)
        abase[m] = (m * 16 + l15) * 296 + kg * 8;

    #pragma unroll 1
    for (int ci0 = 0; ci0 < CCH; ci0 += 32) {
        __syncthreads();
        // stage W: 64 rows x 37 slots (36 data + 1 pad). 2368 = 37*64.
        #pragma unroll
        for (int i = 0; i < 10; ++i) {
            int d = t + i * 256;
            if (d < 2368) {                       // wave-uniform
                int c = d / 37, rem = d - c * 37;
                const _Float16* g = (rem < 36)
                    ? &wvh[(size_t)(co0 + c) * 4608 + (rem >> 2) * 512 + ci0 + (rem & 3) * 8]
                    : wvh;
                gload_lds16(g, (char*)Wl + (size_t)(i * 256 + wv4 * 64) * 16);
            }
        }
        // stage Y: 340 (r,c) x 5 slots (4 data + 1 pad); 1700 -> padded 1728.
        #pragma unroll
        for (int i = 0; i < 7; ++i) {
            int d = t + i * 256;
            if (d < 1728) {                       // wave-uniform (1728 = 27*64)
                int rc = d / 5, part = d - rc * 5;
                const _Float16* g = yp;
                if (rc < 340 && part < 4) {
                    int r = rc / 34, c = rc - r * 34;
                    g = &yp[((size_t)(b * PH + r0p + r) * PH + c) * CCH + ci0 + part * 8];
                }
                gload_lds16(g, (char*)Yl + (size_t)(i * 256 + wv4 * 64) * 16);
            }
        }
        __syncthreads();

        #pragma unroll
        for (int tap = 0; tap < 9; ++tap) {
            const int dh = tap / 3, dw = tap % 3;
            half8 a[4], bf[4];
            #pragma unroll
            for (int m = 0; m < 4; ++m)
                a[m] = *(const half8*)&Wl[abase[m] + tap * 32];
            #pragma unroll
            for (int n = 0; n < 4; ++n)
                bf[n] = *(const half8*)&Yl[bbase[n] + (dh * 34 + dw) * 40];
            #pragma unroll
            for (int m = 0; m < 4; ++m)
                #pragma unroll
                for (int n = 0; n < 4; ++n)
                    acc[m][n] = __builtin_amdgcn_mfma_f32_16x16x32_f16(a[m], bf[n], acc[m][n], 0, 0, 0);
        }
    }

    #pragma unroll
    for (int m = 0; m < 4; ++m) {
        #pragma unroll
        for (int reg = 0; reg < 4; ++reg) {
            int co = co0 + m * 16 + kg * 4 + reg;
            float bias = bvb[co];
            #pragma unroll
            for (int n = 0; n < 4; ++n) {
                int px = pt * 256 + wv4 * 64 + n * 16 + l15;
                vout[((size_t)b * CCH + co) * NN + px] = (_Float16)(acc[m][n][reg] + bias);
            }
        }
    }
}

// ---------------------------------------------------------------------------
// conv_qk_split (unchanged R11): split-K fp16 MFMA conv, gload_lds staging.
// grid(32 = 8pt*4ks, 2 which, 16 b), block 256.
// ---------------------------------------------------------------------------
__global__ __launch_bounds__(256, 4) void conv_qk_split_kernel(
    const _Float16* __restrict__ xp,    // [b][34][34][ci] padded
    const _Float16* __restrict__ yp,    // [b][34][34][ci] padded
    const _Float16* __restrict__ wqkh,  // [which*32+co][tap*512+ci]
    float* __restrict__ pbuf)           // [ks][which][b][px][co] fp32
{
    const int pt    = blockIdx.x >> 2;
    const int ks    = blockIdx.x & 3;
    const int which = blockIdx.y;
    const int b     = blockIdx.z;
    const _Float16* in = which ? yp : xp;

    __shared__ __align__(16) _Float16 Wl[9728];   // 1216 slots (1184 used)
    __shared__ __align__(16) _Float16 Xl[8192];   // 1024 slots (1020 used)

    const int t    = threadIdx.x;
    const int lane = t & 63;
    const int w    = t >> 6;
    const int l15  = lane & 15;
    const int kg   = lane >> 4;

    f32x4 acc[2][2];
    #pragma unroll
    for (int m = 0; m < 2; ++m)
        #pragma unroll
        for (int n = 0; n < 2; ++n) {
            f32x4 z = {0.f, 0.f, 0.f, 0.f};
            acc[m][n] = z;
        }

    const int r0p = pt * 4;
    int bbase[2];
    #pragma unroll
    for (int n = 0; n < 2; ++n) {
        int pxl = w * 32 + n * 16 + l15;
        int rl = pxl >> 5, cl = pxl & 31;
        bbase[n] = (rl * 34 + cl) * 40 + kg * 8;
    }
    int abase[2];
    #pragma unroll
    for (int m = 0; m < 2; ++m)
        abase[m] = (m * 16 + l15) * 296 + kg * 8;

    #pragma unroll 1
    for (int cc = 0; cc < 4; ++cc) {
        const int ci0 = ks * 128 + cc * 32;
        __syncthreads();
        // stage W: 32 rows x 37 slots = 1184, padded to 1216 (19*64).
        #pragma unroll
        for (int i = 0; i < 5; ++i) {
            int d = t + i * 256;
            if (d < 1216) {                       // wave-uniform
                const _Float16* g = wqkh;
                if (d < 1184) {
                    int c = d / 37, rem = d - c * 37;
                    if (rem < 36)
                        g = &wqkh[(size_t)(which * 32 + c) * 4608 + (rem >> 2) * 512 + ci0 + (rem & 3) * 8];
                }
                gload_lds16(g, (char*)Wl + (size_t)(i * 256 + w * 64) * 16);
            }
        }
        // stage X: 204 (r,c) x 5 slots = 1020, padded to 1024 (16*64).
        #pragma unroll
        for (int i = 0; i < 4; ++i) {
            int d = t + i * 256;
            int rc = d / 5, part = d - rc * 5;
            const _Float16* g = in;
            if (rc < 204 && part < 4) {
                int r = rc / 34, c = rc - r * 34;
                g = &in[((size_t)(b * PH + r0p + r) * PH + c) * CCH + ci0 + part * 8];
            }
            gload_lds16(g, (char*)Xl + (size_t)(i * 256 + w * 64) * 16);
        }
        __syncthreads();

        #pragma unroll
        for (int tap = 0; tap < 9; ++tap) {
            const int dh = tap / 3, dw = tap % 3;
            half8 a[2], bfr[2];
            #pragma unroll
            for (int m = 0; m < 2; ++m)
                a[m] = *(const half8*)&Wl[abase[m] + tap * 32];
            #pragma unroll
            for (int n = 0; n < 2; ++n)
                bfr[n] = *(const half8*)&Xl[bbase[n] + (dh * 34 + dw) * 40];
            #pragma unroll
            for (int m = 0; m < 2; ++m)
                #pragma unroll
                for (int n = 0; n < 2; ++n)
                    acc[m][n] = __builtin_amdgcn_mfma_f32_16x16x32_f16(a[m], bfr[n], acc[m][n], 0, 0, 0);
        }
    }

    float* pb = &pbuf[(((size_t)(ks * 2 + which) * BB + b) * NN) * CQD];
    #pragma unroll
    for (int n = 0; n < 2; ++n) {
        int px = pt * 128 + w * 32 + n * 16 + l15;
        #pragma unroll
        for (int m = 0; m < 2; ++m) {
            float4 o = make_float4(acc[m][n][0], acc[m][n][1], acc[m][n][2], acc[m][n][3]);
            *(float4*)&pb[(size_t)px * CQD + m * 16 + kg * 4] = o;
        }
    }
}

// ---------------------------------------------------------------------------
// qk_reduce: sum 4 split-K partials + bias -> fp16 q/k [b][px][d]. (R6)
// ---------------------------------------------------------------------------
__global__ __launch_bounds__(256) void qk_reduce_kernel(
    const float* __restrict__ pbuf,
    const float* __restrict__ bq, const float* __restrict__ bk,
    _Float16* __restrict__ qh, _Float16* __restrict__ kh)
{
    const int gid   = blockIdx.x * 256 + threadIdx.x;
    const int cog   = gid & 7;
    const int px    = (gid >> 3) & 1023;
    const int b     = (gid >> 13) & 15;
    const int which = gid >> 17;

    const size_t base = (((size_t)which * BB + b) * NN + px) * CQD + cog * 4;
    const size_t kstep = (size_t)2 * BB * NN * CQD;
    float4 s = *(const float4*)&pbuf[base];
    #pragma unroll
    for (int ks = 1; ks < 4; ++ks) {
        float4 p = *(const float4*)&pbuf[base + ks * kstep];
        s.x += p.x; s.y += p.y; s.z += p.z; s.w += p.w;
    }
    const float* bias = which ? bk : bq;
    float4 bv = *(const float4*)&bias[cog * 4];
    half4 o;
    o[0] = (_Float16)(s.x + bv.x);
    o[1] = (_Float16)(s.y + bv.y);
    o[2] = (_Float16)(s.z + bv.z);
    o[3] = (_Float16)(s.w + bv.w);
    _Float16* out = which ? kh : qh;
    *(half4*)&out[((size_t)b * NN + px) * CQD + cog * 4] = o;
}

// ---------------------------------------------------------------------------
// attn_fused (R13): 64i x 512c block, 512 threads (8 waves), grid 256 =
// 1 block/CU. V double-buffered in 64c x 128j chunks; each phase ISSUES the
// next chunk's global_load_lds BEFORE its MFMAs (prefetch cover, one barrier
// per phase). K prefetched into alt buffer (pass1) / staged in cc=7 phase
// (pass2). V L2-traffic halved vs 32i blocks. LDS 62.4 KB; red arrays
// overlaid on Vl/Pl.
// ---------------------------------------------------------------------------
__global__ __launch_bounds__(512, 2) void attn_fused_kernel(
    const _Float16* __restrict__ qh,  // [b][i][d]
    const _Float16* __restrict__ kh,  // [b][j][d]
    const _Float16* __restrict__ v,   // [b][c][j]
    float* __restrict__ out)
{
    // XCD swizzle: each XCD owns 2 b's (V 2MB resident in its 4MB L2).
    const int wg   = blockIdx.x;                 // 0..255
    const int virt = (wg & 7) * 32 + (wg >> 3);
    const int b    = virt >> 4;
    const int i0   = (virt & 15) * 64;

    __shared__ __align__(16) _Float16 Kl[128 * 40];      // [j][d+8pad] 10.2 KB
    __shared__ __align__(16) _Float16 Vl[2][64 * 136];   // dbuf [c][128j+8pad] 34.8 KB
    __shared__ __align__(16) _Float16 Pl[64 * 136];      // [i][128j+8pad] 17.4 KB
    _Float16* KlA  = (_Float16*)Vl[1];   // pass-1 alternate K buffer (overlay)
    float*    redm = (float*)Vl[0];      // [64][33] overlay, used between passes
    float*    redl = (float*)Pl;         // [64][33] overlay

    const int t    = threadIdx.x;        // 0..511
    const int lane = t & 63;
    const int w    = t >> 6;             // wave 0..7
    const int l15  = lane & 15;
    const int kg   = lane >> 4;
    const int mc   = w & 3;              // c-frag within 64c chunk (PV)
    const int ih   = w >> 2;             // i-half (PV)

    // K stage: 128 rows x 5 slots (4 data + 1 pad) = 640 slots
    #define STAGE_K(dst, jp_)                                                   \
        {                                                                       \
            _Pragma("unroll")                                                   \
            for (int i_ = 0; i_ < 2; ++i_) {                                    \
                int d_ = t + i_ * 512;                                          \
                if (d_ < 640) {                                                 \
                    int j_ = d_ / 5, rem_ = d_ - j_ * 5;                        \
                    const _Float16* g_ = (rem_ < 4)                             \
                        ? &kh[((size_t)b * NN + (jp_) * 128 + j_) * CQD + rem_ * 8] \
                        : kh;                                                   \
                    gload_lds16(g_, (char*)(dst) + (size_t)(i_ * 512 + w * 64) * 16); \
                }                                                               \
            }                                                                   \
        }
    // V stage: chunk (jp, cc) = 64 c x 128 j; 64 rows x 17 slots = 1088 slots
    #define STAGE_V(dst, jp_, cc_)                                              \
        {                                                                       \
            _Pragma("unroll")                                                   \
            for (int i_ = 0; i_ < 3; ++i_) {                                    \
                int d_ = t + i_ * 512;                                          \
                if (d_ < 1088) {                                                \
                    int r_ = d_ / 17, rem_ = d_ - r_ * 17;                      \
                    const _Float16* g_ = (rem_ < 16)                            \
                        ? &v[((size_t)b * CCH + (cc_) * 64 + r_) * NN + (jp_) * 128 + rem_ * 8] \
                        : v;                                                    \
                    gload_lds16(g_, (char*)(dst) + (size_t)(i_ * 512 + w * 64) * 16); \
                }                                                               \
            }                                                                   \
        }

    // Q B-fragments: i = i0 + n*16 + l15, n = 0..3
    half8 qb[4];
    #pragma unroll
    for (int n = 0; n < 4; ++n)
        qb[n] = *(const half8*)&qh[((size_t)b * NN + i0 + n * 16 + l15) * CQD + kg * 8];

    // ---- pass 1: online softmax stats, K double-buffered (Kl / KlA) ----
    float m[4] = {-3.0e38f, -3.0e38f, -3.0e38f, -3.0e38f};
    float l[4] = {0.f, 0.f, 0.f, 0.f};
    STAGE_K(Kl, 0);
    __syncthreads();
    #pragma unroll 1
    for (int jp = 0; jp < 8; ++jp) {
        const _Float16* kcur = (jp & 1) ? KlA : Kl;
        _Float16* knxt = (jp & 1) ? Kl : KlA;
        if (jp < 7) STAGE_K(knxt, jp + 1);
        half8 ak = *(const half8*)&kcur[(w * 16 + l15) * 40 + kg * 8];
        #pragma unroll
        for (int n = 0; n < 4; ++n) {
            f32x4 s = {0.f, 0.f, 0.f, 0.f};
            s = __builtin_amdgcn_mfma_f32_16x16x32_f16(ak, qb[n], s, 0, 0, 0);
            float tm = fmaxf(fmaxf(s[0], s[1]), fmaxf(s[2], s[3]));
            float m2 = fmaxf(m[n], tm);
            l[n] = l[n] * __expf(m[n] - m2)
                 + __expf(s[0] - m2) + __expf(s[1] - m2)
                 + __expf(s[2] - m2) + __expf(s[3] - m2);
            m[n] = m2;
        }
        __syncthreads();
    }
    // cross-(wave,kg) reduce: 32 partials per i, via overlaid red arrays
    #pragma unroll
    for (int n = 0; n < 4; ++n) {
        redm[(n * 16 + l15) * 33 + w * 4 + kg] = m[n];
        redl[(n * 16 + l15) * 33 + w * 4 + kg] = l[n];
    }
    __syncthreads();
    float mr[4], rl[4];
    #pragma unroll
    for (int n = 0; n < 4; ++n) {
        const int i = n * 16 + l15;
        float M = redm[i * 33];
        #pragma unroll
        for (int p = 1; p < 32; ++p) M = fmaxf(M, redm[i * 33 + p]);
        float L = 0.f;
        #pragma unroll
        for (int p = 0; p < 32; ++p) L += redl[i * 33 + p] * __expf(redm[i * 33 + p] - M);
        mr[n] = M;
        rl[n] = 1.f / L;
    }
    __syncthreads();   // red reads done before V(0,0) overwrites Vl[0]

    // ---- pass 2: prefetch-pipelined PV ----
    f32x4 acc[8][2];
    #pragma unroll
    for (int cc = 0; cc < 8; ++cc)
        #pragma unroll
        for (int nl = 0; nl < 2; ++nl) {
            f32x4 z = {0.f, 0.f, 0.f, 0.f};
            acc[cc][nl] = z;
        }

    STAGE_K(Kl, 0);
    STAGE_V(Vl[0], 0, 0);
    __syncthreads();

    #pragma unroll 1
    for (int jp = 0; jp < 8; ++jp) {
        // S phase: P[64i][128j] (wave w owns j-rows w*16..+15)
        {
            half8 ak = *(const half8*)&Kl[(w * 16 + l15) * 40 + kg * 8];
            #pragma unroll
            for (int n = 0; n < 4; ++n) {
                f32x4 s = {0.f, 0.f, 0.f, 0.f};
                s = __builtin_amdgcn_mfma_f32_16x16x32_f16(ak, qb[n], s, 0, 0, 0);
                half4 p4;
                #pragma unroll
                for (int reg = 0; reg < 4; ++reg)
                    p4[reg] = (_Float16)(__expf(s[reg] - mr[n]) * rl[n]);
                *(half4*)&Pl[(n * 16 + l15) * 136 + w * 16 + kg * 4] = p4;
            }
        }
        __syncthreads();
        // 8 cc phases: issue next stage, then 8 MFMA, then barrier
        #pragma unroll
        for (int cc = 0; cc < 8; ++cc) {
            if (cc < 7) {
                _Float16* vnxt = (cc & 1) ? (_Float16*)Vl[0] : (_Float16*)Vl[1];
                STAGE_V(vnxt, jp, cc + 1);
            } else if (jp < 7) {
                STAGE_K(Kl, jp + 1);
                STAGE_V(Vl[0], jp + 1, 0);
            }
            const _Float16* vcur = (cc & 1) ? (const _Float16*)Vl[1]
                                            : (const _Float16*)Vl[0];
            #pragma unroll
            for (int ks = 0; ks < 4; ++ks) {
                half8 va = *(const half8*)&vcur[(mc * 16 + l15) * 136 + ks * 32 + kg * 8];
                #pragma unroll
                for (int nl = 0; nl < 2; ++nl) {
                    half8 pbf = *(const half8*)&Pl[((ih * 2 + nl) * 16 + l15) * 136 + ks * 32 + kg * 8];
                    acc[cc][nl] = __builtin_amdgcn_mfma_f32_16x16x32_f16(va, pbf, acc[cc][nl], 0, 0, 0);
                }
            }
            __syncthreads();
        }
    }

    // epilogue: c = cc*64 + mc*16 + kg*4+reg; i = i0 + ih*32 + nl*16 + l15
    #pragma unroll
    for (int cc = 0; cc < 8; ++cc)
        #pragma unroll
        for (int nl = 0; nl < 2; ++nl)
            #pragma unroll
            for (int reg = 0; reg < 4; ++reg) {
                int c = cc * 64 + mc * 16 + kg * 4 + reg;
                out[((size_t)b * CCH + c) * NN + i0 + ih * 32 + nl * 16 + l15] = acc[cc][nl][reg];
            }
    #undef STAGE_K
    #undef STAGE_V
}

// ---------------------------------------------------------------------------
extern "C" void kernel_launch(void* const* d_in, const int* in_sizes, int n_in,
                              void* d_out, int out_size, void* d_ws, size_t ws_size,
                              hipStream_t stream) {
    const float* x  = (const float*)d_in[0];
    const float* y  = (const float*)d_in[1];
    const float* wq = (const float*)d_in[2];
    const float* bq = (const float*)d_in[3];
    const float* wk = (const float*)d_in[4];
    const float* bk = (const float*)d_in[5];
    const float* wv = (const float*)d_in[6];
    const float* bv = (const float*)d_in[7];
    float* out = (float*)d_out;

    // ws layout: qh(1M) kh(1M) | v(16.8M) | yp(18.9M) xp(18.9M) padded imgs |
    //            wvh(4.7M) wqkh(0.6M)   total ~62M
    // pbuf (split-K fp32 partials, 16.8M) ALIASES v: consumed by qk_reduce
    // before conv_v_mfma writes v (same stream, serialized).
    _Float16* qhb = (_Float16*)d_ws;
    _Float16* khb = qhb + (size_t)BB * NN * CQD;
    _Float16* vb   = khb + (size_t)BB * NN * CQD;
    _Float16* ypb  = vb + (size_t)BB * CCH * NN;
    _Float16* xpb  = ypb + (size_t)BB * PH * PH * CCH;
    _Float16* wvh  = xpb + (size_t)BB * PH * PH * CCH;
    _Float16* wqkh = wvh + (size_t)512 * 4608;
    float* pbuf = (float*)vb;

    prep_img_kernel<<<dim3(PH, 2, BB), 256, 0, stream>>>(x, y, xpb, ypb);
    prep_w_all_kernel<<<dim3(576), 256, 0, stream>>>(wv, wq, wk, wvh, wqkh);
    conv_qk_split_kernel<<<dim3(32, 2, BB), 256, 0, stream>>>(xpb, ypb, wqkh, pbuf);
    qk_reduce_kernel<<<dim3(1024), 256, 0, stream>>>(pbuf, bq, bk, qhb, khb);
    conv_v_mfma_kernel<<<dim3(4, 8, BB), 256, 0, stream>>>(ypb, wvh, bv, vb);
    attn_fused_kernel<<<dim3(256), 512, 0, stream>>>(qhb, khb, vb, out);
}

// Round 14
// 169.311 us; speedup vs baseline: 1.1971x; 1.1971x over previous
//
#include <hip/hip_runtime.h>

// Problem constants
#define BB 16
#define CCH 512
#define CQD 32
#define HH 32
#define WW 32
#define NN 1024
#define PH 34   // padded image dim

typedef __attribute__((ext_vector_type(8))) _Float16 half8;
typedef __attribute__((ext_vector_type(4))) _Float16 half4;
typedef __attribute__((ext_vector_type(4))) float f32x4;

// async global->LDS, 16B per lane; lds dest = wave-uniform base + lane*16
static __device__ __forceinline__ void gload_lds16(const void* g, void* l) {
    __builtin_amdgcn_global_load_lds(
        (const __attribute__((address_space(1))) unsigned int*)g,
        (__attribute__((address_space(3))) unsigned int*)l, 16, 0, 0);
}

// ---------------------------------------------------------------------------
// prep_img: img[b][ci][h][w] fp32 -> imgp[b][34][34][ci] fp16, zero halo.
// grid(34 padded rows, 2 which, 16 b), block 256
// ---------------------------------------------------------------------------
__global__ __launch_bounds__(256) void prep_img_kernel(
    const float* __restrict__ x, const float* __restrict__ y,
    _Float16* __restrict__ xp, _Float16* __restrict__ yp)
{
    const int h = blockIdx.x;            // padded row 0..33
    const int which = blockIdx.y, b = blockIdx.z;
    const float* img = which ? y : x;
    _Float16* row = (which ? yp : xp) + (size_t)(b * PH + h) * PH * CCH;
    const int t = threadIdx.x;
    const int gh = h - 1;

    half8 z;
    #pragma unroll
    for (int u = 0; u < 8; ++u) z[u] = (_Float16)0.f;

    if (gh < 0 || gh >= HH) {            // border row: all zeros (34*512 halves)
        for (int idx = t; idx < PH * CCH / 8; idx += 256)
            *(half8*)&row[(size_t)idx * 8] = z;
        return;
    }

    __shared__ float X[64][33];
    for (int ci0 = 0; ci0 < CCH; ci0 += 64) {
        __syncthreads();
        #pragma unroll
        for (int i = 0; i < 8; ++i) {
            int ci = i * 8 + (t >> 5), w = t & 31;
            X[ci][w] = img[((size_t)(b * CCH + ci0 + ci) * HH + gh) * WW + w];
        }
        __syncthreads();
        int w = t >> 3, g = t & 7;
        half8 o;
        #pragma unroll
        for (int u = 0; u < 8; ++u) o[u] = (_Float16)X[g * 8 + u][w];
        *(half8*)&row[(size_t)(w + 1) * CCH + ci0 + g * 8] = o;
        if (t < 16) {                    // zero pad cols 0 and 33 for this chunk
            int col = (t < 8) ? 0 : 33;
            *(half8*)&row[(size_t)col * CCH + ci0 + (t & 7) * 8] = z;
        }
    }
}

// ---------------------------------------------------------------------------
// prep_w_all: wv -> wvh[0..511], wq -> wqkh[0..31], wk -> wqkh[32..63]
// layout [co][tap*512+ci] fp16. grid(576), block 256.
// ---------------------------------------------------------------------------
__global__ __launch_bounds__(256) void prep_w_all_kernel(
    const float* __restrict__ wv, const float* __restrict__ wq,
    const float* __restrict__ wk, _Float16* __restrict__ wvh,
    _Float16* __restrict__ wqkh)
{
    const int bid = blockIdx.x;
    const float* src;
    _Float16* dst;
    int co_src, co_dst;
    if (bid < 512)      { src = wv; co_src = bid;       dst = wvh;  co_dst = bid; }
    else if (bid < 544) { src = wq; co_src = bid - 512; dst = wqkh; co_dst = bid - 512; }
    else                { src = wk; co_src = bid - 544; dst = wqkh; co_dst = 32 + (bid - 544); }
    for (int idx = threadIdx.x; idx < 4608; idx += 256) {
        int tap = idx / 512, ci = idx - tap * 512;
        dst[(size_t)co_dst * 4608 + idx] = (_Float16)src[(size_t)co_src * 4608 + ci * 9 + tap];
    }
}

// ---------------------------------------------------------------------------
// conv_v_mfma (unchanged R11): W and Y staged via global_load_lds width=16.
// grid(4 pxtiles, 8 cotiles, 16 b), block 256.
// ---------------------------------------------------------------------------
__global__ __launch_bounds__(256, 2) void conv_v_mfma_kernel(
    const _Float16* __restrict__ yp,    // [b][34][34][ci] padded
    const _Float16* __restrict__ wvh,   // [co][tap*512+ci]
    const float* __restrict__ bvb,
    _Float16* __restrict__ vout)        // fp16 [b][co][px]
{
    const int pt  = blockIdx.x;
    const int co0 = blockIdx.y * 64;
    const int b   = blockIdx.z;

    __shared__ __align__(16) _Float16 Wl[64 * 296];   // 2368 16B slots
    __shared__ __align__(16) _Float16 Yl[13824];      // 1728 16B slots (1700 used)

    const int t    = threadIdx.x;
    const int lane = t & 63;
    const int wv4  = t >> 6;
    const int l15  = lane & 15;
    const int kg   = lane >> 4;

    f32x4 acc[4][4];
    #pragma unroll
    for (int m = 0; m < 4; ++m)
        #pragma unroll
        for (int n = 0; n < 4; ++n) {
            f32x4 z = {0.f, 0.f, 0.f, 0.f};
            acc[m][n] = z;
        }

    const int r0p = pt * 8;              // padded start row
    int bbase[4];
    #pragma unroll
    for (int n = 0; n < 4; ++n) {
        int pxl = wv4 * 64 + n * 16 + l15;
        int rl = pxl >> 5, cl = pxl & 31;
        bbase[n] = (rl * 34 + cl) * 40 + kg * 8;
    }
    int abase[4];
    #pragma unroll
    for (int m = 0; m < 4; ++m)
        abase[m] = (m * 16 + l15) * 296 + kg * 8;

    #pragma unroll 1
    for (int ci0 = 0; ci0 < CCH; ci0 += 32) {
        __syncthreads();
        // stage W: 64 rows x 37 slots (36 data + 1 pad). 2368 = 37*64.
        #pragma unroll
        for (int i = 0; i < 10; ++i) {
            int d = t + i * 256;
            if (d < 2368) {                       // wave-uniform
                int c = d / 37, rem = d - c * 37;
                const _Float16* g = (rem < 36)
                    ? &wvh[(size_t)(co0 + c) * 4608 + (rem >> 2) * 512 + ci0 + (rem & 3) * 8]
                    : wvh;
                gload_lds16(g, (char*)Wl + (size_t)(i * 256 + wv4 * 64) * 16);
            }
        }
        // stage Y: 340 (r,c) x 5 slots (4 data + 1 pad); 1700 -> padded 1728.
        #pragma unroll
        for (int i = 0; i < 7; ++i) {
            int d = t + i * 256;
            if (d < 1728) {                       // wave-uniform (1728 = 27*64)
                int rc = d / 5, part = d - rc * 5;
                const _Float16* g = yp;
                if (rc < 340 && part < 4) {
                    int r = rc / 34, c = rc - r * 34;
                    g = &yp[((size_t)(b * PH + r0p + r) * PH + c) * CCH + ci0 + part * 8];
                }
                gload_lds16(g, (char*)Yl + (size_t)(i * 256 + wv4 * 64) * 16);
            }
        }
        __syncthreads();

        #pragma unroll
        for (int tap = 0; tap < 9; ++tap) {
            const int dh = tap / 3, dw = tap % 3;
            half8 a[4], bf[4];
            #pragma unroll
            for (int m = 0; m < 4; ++m)
                a[m] = *(const half8*)&Wl[abase[m] + tap * 32];
            #pragma unroll
            for (int n = 0; n < 4; ++n)
                bf[n] = *(const half8*)&Yl[bbase[n] + (dh * 34 + dw) * 40];
            #pragma unroll
            for (int m = 0; m < 4; ++m)
                #pragma unroll
                for (int n = 0; n < 4; ++n)
                    acc[m][n] = __builtin_amdgcn_mfma_f32_16x16x32_f16(a[m], bf[n], acc[m][n], 0, 0, 0);
        }
    }

    #pragma unroll
    for (int m = 0; m < 4; ++m) {
        #pragma unroll
        for (int reg = 0; reg < 4; ++reg) {
            int co = co0 + m * 16 + kg * 4 + reg;
            float bias = bvb[co];
            #pragma unroll
            for (int n = 0; n < 4; ++n) {
                int px = pt * 256 + wv4 * 64 + n * 16 + l15;
                vout[((size_t)b * CCH + co) * NN + px] = (_Float16)(acc[m][n][reg] + bias);
            }
        }
    }
}

// ---------------------------------------------------------------------------
// conv_qk_split (unchanged R11): split-K fp16 MFMA conv, gload_lds staging.
// grid(32 = 8pt*4ks, 2 which, 16 b), block 256.
// ---------------------------------------------------------------------------
__global__ __launch_bounds__(256, 4) void conv_qk_split_kernel(
    const _Float16* __restrict__ xp,    // [b][34][34][ci] padded
    const _Float16* __restrict__ yp,    // [b][34][34][ci] padded
    const _Float16* __restrict__ wqkh,  // [which*32+co][tap*512+ci]
    float* __restrict__ pbuf)           // [ks][which][b][px][co] fp32
{
    const int pt    = blockIdx.x >> 2;
    const int ks    = blockIdx.x & 3;
    const int which = blockIdx.y;
    const int b     = blockIdx.z;
    const _Float16* in = which ? yp : xp;

    __shared__ __align__(16) _Float16 Wl[9728];   // 1216 slots (1184 used)
    __shared__ __align__(16) _Float16 Xl[8192];   // 1024 slots (1020 used)

    const int t    = threadIdx.x;
    const int lane = t & 63;
    const int w    = t >> 6;
    const int l15  = lane & 15;
    const int kg   = lane >> 4;

    f32x4 acc[2][2];
    #pragma unroll
    for (int m = 0; m < 2; ++m)
        #pragma unroll
        for (int n = 0; n < 2; ++n) {
            f32x4 z = {0.f, 0.f, 0.f, 0.f};
            acc[m][n] = z;
        }

    const int r0p = pt * 4;
    int bbase[2];
    #pragma unroll
    for (int n = 0; n < 2; ++n) {
        int pxl = w * 32 + n * 16 + l15;
        int rl = pxl >> 5, cl = pxl & 31;
        bbase[n] = (rl * 34 + cl) * 40 + kg * 8;
    }
    int abase[2];
    #pragma unroll
    for (int m = 0; m < 2; ++m)
        abase[m] = (m * 16 + l15) * 296 + kg * 8;

    #pragma unroll 1
    for (int cc = 0; cc < 4; ++cc) {
        const int ci0 = ks * 128 + cc * 32;
        __syncthreads();
        // stage W: 32 rows x 37 slots = 1184, padded to 1216 (19*64).
        #pragma unroll
        for (int i = 0; i < 5; ++i) {
            int d = t + i * 256;
            if (d < 1216) {                       // wave-uniform
                const _Float16* g = wqkh;
                if (d < 1184) {
                    int c = d / 37, rem = d - c * 37;
                    if (rem < 36)
                        g = &wqkh[(size_t)(which * 32 + c) * 4608 + (rem >> 2) * 512 + ci0 + (rem & 3) * 8];
                }
                gload_lds16(g, (char*)Wl + (size_t)(i * 256 + w * 64) * 16);
            }
        }
        // stage X: 204 (r,c) x 5 slots = 1020, padded to 1024 (16*64).
        #pragma unroll
        for (int i = 0; i < 4; ++i) {
            int d = t + i * 256;
            int rc = d / 5, part = d - rc * 5;
            const _Float16* g = in;
            if (rc < 204 && part < 4) {
                int r = rc / 34, c = rc - r * 34;
                g = &in[((size_t)(b * PH + r0p + r) * PH + c) * CCH + ci0 + part * 8];
            }
            gload_lds16(g, (char*)Xl + (size_t)(i * 256 + w * 64) * 16);
        }
        __syncthreads();

        #pragma unroll
        for (int tap = 0; tap < 9; ++tap) {
            const int dh = tap / 3, dw = tap % 3;
            half8 a[2], bfr[2];
            #pragma unroll
            for (int m = 0; m < 2; ++m)
                a[m] = *(const half8*)&Wl[abase[m] + tap * 32];
            #pragma unroll
            for (int n = 0; n < 2; ++n)
                bfr[n] = *(const half8*)&Xl[bbase[n] + (dh * 34 + dw) * 40];
            #pragma unroll
            for (int m = 0; m < 2; ++m)
                #pragma unroll
                for (int n = 0; n < 2; ++n)
                    acc[m][n] = __builtin_amdgcn_mfma_f32_16x16x32_f16(a[m], bfr[n], acc[m][n], 0, 0, 0);
        }
    }

    float* pb = &pbuf[(((size_t)(ks * 2 + which) * BB + b) * NN) * CQD];
    #pragma unroll
    for (int n = 0; n < 2; ++n) {
        int px = pt * 128 + w * 32 + n * 16 + l15;
        #pragma unroll
        for (int m = 0; m < 2; ++m) {
            float4 o = make_float4(acc[m][n][0], acc[m][n][1], acc[m][n][2], acc[m][n][3]);
            *(float4*)&pb[(size_t)px * CQD + m * 16 + kg * 4] = o;
        }
    }
}

// ---------------------------------------------------------------------------
// qk_reduce: sum 4 split-K partials + bias -> fp16 q/k [b][px][d]. (R6)
// ---------------------------------------------------------------------------
__global__ __launch_bounds__(256) void qk_reduce_kernel(
    const float* __restrict__ pbuf,
    const float* __restrict__ bq, const float* __restrict__ bk,
    _Float16* __restrict__ qh, _Float16* __restrict__ kh)
{
    const int gid   = blockIdx.x * 256 + threadIdx.x;
    const int cog   = gid & 7;
    const int px    = (gid >> 3) & 1023;
    const int b     = (gid >> 13) & 15;
    const int which = gid >> 17;

    const size_t base = (((size_t)which * BB + b) * NN + px) * CQD + cog * 4;
    const size_t kstep = (size_t)2 * BB * NN * CQD;
    float4 s = *(const float4*)&pbuf[base];
    #pragma unroll
    for (int ks = 1; ks < 4; ++ks) {
        float4 p = *(const float4*)&pbuf[base + ks * kstep];
        s.x += p.x; s.y += p.y; s.z += p.z; s.w += p.w;
    }
    const float* bias = which ? bk : bq;
    float4 bv = *(const float4*)&bias[cog * 4];
    half4 o;
    o[0] = (_Float16)(s.x + bv.x);
    o[1] = (_Float16)(s.y + bv.y);
    o[2] = (_Float16)(s.z + bv.z);
    o[3] = (_Float16)(s.w + bv.w);
    _Float16* out = which ? kh : qh;
    *(half4*)&out[((size_t)b * NN + px) * CQD + cog * 4] = o;
}

// ---------------------------------------------------------------------------
// attn_fused (R14): R12 geometry (32i x 512c, 256 thr, grid 512, 2 blk/CU).
// Changes vs R12:
//  - K never staged in LDS: a wave's K fragment is a 1KB fully-coalesced
//    direct global load (K[b]=64KB, L2-resident). Pass 1 has ZERO barriers.
//  - V double-buffered (2 x 128c x 136); stage issued at PHASE START:
//    {barrier; issue V(next); compute(cur)} -> full-phase cover per stage.
//    5 barriers/jp (was ~11). Red arrays overlaid on Pl (LDS 78.3KB).
// ---------------------------------------------------------------------------
__global__ __launch_bounds__(256, 2) void attn_fused_kernel(
    const _Float16* __restrict__ qh,  // [b][i][d]
    const _Float16* __restrict__ kh,  // [b][j][d]
    const _Float16* __restrict__ v,   // [b][c][j]
    float* __restrict__ out)
{
    const int wg   = blockIdx.x;                 // 0..511
    const int virt = (wg & 7) * 64 + (wg >> 3);  // XCD swizzle: 2 b's per XCD
    const int b    = virt >> 5;
    const int i0   = (virt & 31) * 32;

    __shared__ __align__(16) _Float16 Vl[2][128 * 136];  // dbuf [c][128j+8pad] 69.6KB
    __shared__ __align__(16) _Float16 Pl[32 * 136];      // [i][128j+8pad] 8.7KB
    float* redm = (float*)Pl;            // [32][17] overlay (pass1->pass2 only)
    float* redl = redm + 32 * 17;

    const int t    = threadIdx.x;
    const int lane = t & 63;
    const int w    = t >> 6;
    const int l15  = lane & 15;
    const int kg   = lane >> 4;

    // V stage: chunk (jp, cc) = 128 c x 128 j; 128 rows x 17 slots = 2176 = 8.5*256
    #define STAGE_V(dst, jp_, cc_)                                              \
        {                                                                       \
            _Pragma("unroll")                                                   \
            for (int i_ = 0; i_ < 9; ++i_) {                                    \
                int d_ = t + i_ * 256;                                          \
                if (d_ < 2176) {                  /* wave-uniform (2176=34*64) */\
                    int r_ = d_ / 17, rem_ = d_ - r_ * 17;                      \
                    const _Float16* g_ = (rem_ < 16)                            \
                        ? &v[((size_t)b * CCH + (cc_) * 128 + r_) * NN + (jp_) * 128 + rem_ * 8] \
                        : v;                                                    \
                    gload_lds16(g_, (char*)(dst) + (size_t)(i_ * 256 + w * 64) * 16); \
                }                                                               \
            }                                                                   \
        }

    // Q B-fragments (i = i0 + n*16 + l15)
    half8 qb[2];
    #pragma unroll
    for (int n = 0; n < 2; ++n)
        qb[n] = *(const half8*)&qh[((size_t)b * NN + i0 + n * 16 + l15) * CQD + kg * 8];

    // ---- pass 1: online softmax stats, direct K loads, NO barriers ----
    float m[2] = {-3.0e38f, -3.0e38f}, l[2] = {0.f, 0.f};
    #pragma unroll 1
    for (int jp = 0; jp < 8; ++jp) {
        #pragma unroll
        for (int ht = 0; ht < 2; ++ht) {
            int j = jp * 128 + ht * 64 + w * 16 + l15;
            half8 ak = *(const half8*)&kh[((size_t)b * NN + j) * CQD + kg * 8];
            #pragma unroll
            for (int n = 0; n < 2; ++n) {
                f32x4 s = {0.f, 0.f, 0.f, 0.f};
                s = __builtin_amdgcn_mfma_f32_16x16x32_f16(ak, qb[n], s, 0, 0, 0);
                float tm = fmaxf(fmaxf(s[0], s[1]), fmaxf(s[2], s[3]));
                float m2 = fmaxf(m[n], tm);
                l[n] = l[n] * __expf(m[n] - m2)
                     + __expf(s[0] - m2) + __expf(s[1] - m2)
                     + __expf(s[2] - m2) + __expf(s[3] - m2);
                m[n] = m2;
            }
        }
    }
    // cross-(wave,kg) reduce per i via overlay on Pl
    #pragma unroll
    for (int n = 0; n < 2; ++n) {
        redm[(n * 16 + l15) * 17 + w * 4 + kg] = m[n];
        redl[(n * 16 + l15) * 17 + w * 4 + kg] = l[n];
    }
    __syncthreads();
    float mr[2], rl[2];
    #pragma unroll
    for (int n = 0; n < 2; ++n) {
        const int i = n * 16 + l15;
        float M = redm[i * 17];
        #pragma unroll
        for (int p = 1; p < 16; ++p) M = fmaxf(M, redm[i * 17 + p]);
        float L = 0.f;
        #pragma unroll
        for (int p = 0; p < 16; ++p) L += redl[i * 17 + p] * __expf(redm[i * 17 + p] - M);
        mr[n] = M;
        rl[n] = 1.f / L;
    }

    // ---- pass 2: stage-early pipelined PV ----
    f32x4 acc[4][2][2];
    #pragma unroll
    for (int cc = 0; cc < 4; ++cc)
        #pragma unroll
        for (int mm = 0; mm < 2; ++mm)
            #pragma unroll
            for (int n = 0; n < 2; ++n) {
                f32x4 z = {0.f, 0.f, 0.f, 0.f};
                acc[cc][mm][n] = z;
            }

    #pragma unroll 1
    for (int jp = 0; jp < 8; ++jp) {
        __syncthreads();                       // all red reads / prev PV done
        STAGE_V(Vl[0], jp, 0);                 // covered by S phase below
        // S phase: direct K, P = exp(S-m)/l -> Pl
        #pragma unroll
        for (int ht = 0; ht < 2; ++ht) {
            int j = jp * 128 + ht * 64 + w * 16 + l15;
            half8 ak = *(const half8*)&kh[((size_t)b * NN + j) * CQD + kg * 8];
            #pragma unroll
            for (int n = 0; n < 2; ++n) {
                f32x4 s = {0.f, 0.f, 0.f, 0.f};
                s = __builtin_amdgcn_mfma_f32_16x16x32_f16(ak, qb[n], s, 0, 0, 0);
                half4 p4;
                #pragma unroll
                for (int reg = 0; reg < 4; ++reg)
                    p4[reg] = (_Float16)(__expf(s[reg] - mr[n]) * rl[n]);
                *(half4*)&Pl[(n * 16 + l15) * 136 + ht * 64 + w * 16 + kg * 4] = p4;
            }
        }
        // 4 cc-phases: {barrier; issue next V; 8 MFMA on current V}
        #pragma unroll
        for (int cc = 0; cc < 4; ++cc) {
            __syncthreads();                   // drains V(jp,cc); Pl ready (cc=0)
            if (cc < 3) {
                _Float16* vnxt = (_Float16*)Vl[(cc + 1) & 1];
                STAGE_V(vnxt, jp, cc + 1);     // covered by this phase's MFMAs
            }
            const _Float16* vcur = (const _Float16*)Vl[cc & 1];
            #pragma unroll
            for (int ks = 0; ks < 4; ++ks) {
                half8 pb[2], va[2];
                #pragma unroll
                for (int n = 0; n < 2; ++n)
                    pb[n] = *(const half8*)&Pl[(n * 16 + l15) * 136 + ks * 32 + kg * 8];
                #pragma unroll
                for (int mm = 0; mm < 2; ++mm)
                    va[mm] = *(const half8*)&vcur[(w * 32 + mm * 16 + l15) * 136 + ks * 32 + kg * 8];
                #pragma unroll
                for (int mm = 0; mm < 2; ++mm)
                    #pragma unroll
                    for (int n = 0; n < 2; ++n)
                        acc[cc][mm][n] = __builtin_amdgcn_mfma_f32_16x16x32_f16(va[mm], pb[n], acc[cc][mm][n], 0, 0, 0);
            }
        }
    }

    // epilogue: D[row=c][col=i]
    #pragma unroll
    for (int cc = 0; cc < 4; ++cc)
        #pragma unroll
        for (int mm = 0; mm < 2; ++mm)
            #pragma unroll
            for (int n = 0; n < 2; ++n)
                #pragma unroll
                for (int reg = 0; reg < 4; ++reg) {
                    int c = cc * 128 + w * 32 + mm * 16 + kg * 4 + reg;
                    out[((size_t)b * CCH + c) * NN + i0 + n * 16 + l15] = acc[cc][mm][n][reg];
                }
    #undef STAGE_V
}

// ---------------------------------------------------------------------------
extern "C" void kernel_launch(void* const* d_in, const int* in_sizes, int n_in,
                              void* d_out, int out_size, void* d_ws, size_t ws_size,
                              hipStream_t stream) {
    const float* x  = (const float*)d_in[0];
    const float* y  = (const float*)d_in[1];
    const float* wq = (const float*)d_in[2];
    const float* bq = (const float*)d_in[3];
    const float* wk = (const float*)d_in[4];
    const float* bk = (const float*)d_in[5];
    const float* wv = (const float*)d_in[6];
    const float* bv = (const float*)d_in[7];
    float* out = (float*)d_out;

    // ws layout: qh(1M) kh(1M) | v(16.8M) | yp(18.9M) xp(18.9M) padded imgs |
    //            wvh(4.7M) wqkh(0.6M)   total ~62M
    // pbuf (split-K fp32 partials, 16.8M) ALIASES v: consumed by qk_reduce
    // before conv_v_mfma writes v (same stream, serialized).
    _Float16* qhb = (_Float16*)d_ws;
    _Float16* khb = qhb + (size_t)BB * NN * CQD;
    _Float16* vb   = khb + (size_t)BB * NN * CQD;
    _Float16* ypb  = vb + (size_t)BB * CCH * NN;
    _Float16* xpb  = ypb + (size_t)BB * PH * PH * CCH;
    _Float16* wvh  = xpb + (size_t)BB * PH * PH * CCH;
    _Float16* wqkh = wvh + (size_t)512 * 4608;
    float* pbuf = (float*)vb;

    prep_img_kernel<<<dim3(PH, 2, BB), 256, 0, stream>>>(x, y, xpb, ypb);
    prep_w_all_kernel<<<dim3(576), 256, 0, stream>>>(wv, wq, wk, wvh, wqkh);
    conv_qk_split_kernel<<<dim3(32, 2, BB), 256, 0, stream>>>(xpb, ypb, wqkh, pbuf);
    qk_reduce_kernel<<<dim3(1024), 256, 0, stream>>>(pbuf, bq, bk, qhb, khb);
    conv_v_mfma_kernel<<<dim3(4, 8, BB), 256, 0, stream>>>(ypb, wvh, bv, vb);
    attn_fused_kernel<<<dim3(512), 256, 0, stream>>>(qhb, khb, vb, out);
}